// Round 16
// baseline (859.480 us; speedup 1.0000x reference)
//
#include <hip/hip_runtime.h>
#include <stdint.h>
#include <math.h>

#define B_   32
#define N_   1024
#define U_   32
#define E_   64
#define LIT_ 12
#define SEM_ 16
#define GBN  64   // 2 graphs * 32 batch

typedef float f32x4 __attribute__((ext_vector_type(4)));
typedef short s16x8 __attribute__((ext_vector_type(8)));
typedef __fp16 h16x2 __attribute__((ext_vector_type(2)));
#define MFMA_BF16(a,b,c) __builtin_amdgcn_mfma_f32_16x16x32_bf16(a,b,c,0,0,0)

#if __has_builtin(__builtin_amdgcn_fdot2)
#define HAVE_FDOT2 1
#else
#define HAVE_FDOT2 0
#endif

// ---------------- primary (bit-packed cfg) layout ----------------
#define F_ET0H 0ULL
#define F_ET1H 16777216ULL
#define F_ET1L 25165824ULL      // part
#define F_EBUF 33554432ULL
#define F_CFGB 50331648ULL      // 8388608 bit-packed cfg
#define F_WBUF 58720256ULL      // 32768 (wT hi/lo, 2 layers)
#define F_MIN  58753024ULL

// ---------------- fp32 fallback layout ----------------
#define O_XPROJ 0ULL
#define O_T     25165824ULL
#define O_E     41943040ULL
#define O_OW    58720256ULL
#define O_MIN   58736640ULL

#define LITBLK 2048             // literal blocks in k_pre (256 thr, 32 rows each)

__device__ __forceinline__ float rdlane(float v, int k) {
    return __int_as_float(__builtin_amdgcn_readlane(__float_as_int(v), k));
}
__device__ __forceinline__ unsigned short bf16rne(float x) {
    unsigned u = __float_as_uint(x);
    return (unsigned short)((u + 0x7FFFu + ((u >> 16) & 1u)) >> 16);
}
__device__ __forceinline__ void hilo(float x, short& h, short& l) {
    unsigned short hb = bf16rne(x);
    float hf = __uint_as_float(((unsigned)hb) << 16);
    h = (short)hb;
    l = (short)bf16rne(x - hf);
}
__device__ __forceinline__ unsigned pkrtz(float a, float b) {
    union { h16x2 h; unsigned u; } c;
    c.h = __builtin_amdgcn_cvt_pkrtz(a, b);
    return c.u;
}
__device__ __forceinline__ h16x2 u2h(unsigned u) {
    union { unsigned u; h16x2 h; } c; c.u = u; return c.h;
}

// ---------- k_pre: literal path (wave-per-row, barrier-free) + cfg bit-pack + W prep ----
__global__ __launch_bounds__(256) void k_pre(
    const float* __restrict__ lit1, const float* __restrict__ sem1,
    const float* __restrict__ lit2, const float* __restrict__ sem2,
    const float* __restrict__ Win1, const float* __restrict__ bin1,
    const float* __restrict__ Wout1, const float* __restrict__ bout1,
    const float* __restrict__ gk1, const float* __restrict__ gb1,
    const float* __restrict__ Win2, const float* __restrict__ bin2,
    const float* __restrict__ Wout2, const float* __restrict__ bout2,
    const float* __restrict__ gk2, const float* __restrict__ gb2,
    float* __restrict__ ebuf, float* __restrict__ xproj,
    const int* __restrict__ c1, const int* __restrict__ c2,
    uint8_t* __restrict__ cfgb,
    const float* __restrict__ mlpW, short* __restrict__ wbuf)
{
    const int tid = threadIdx.x;
    if (blockIdx.x >= LITBLK) {
        if (blockIdx.x <= LITBLK + 4095) {
            // ---- bit-pack cfg: 8 int32 -> 1 byte ----
            int g = blockIdx.x - LITBLK;               // 0..4095
            long long gt = (long long)g * 256 + tid;   // 0..1048575
            #pragma unroll 4
            for (int it = 0; it < 8; ++it) {
                long long o = gt + 1048576LL * it;     // byte index 0..8388607
                const int* src = (o < 4194304LL) ? c1 : c2;
                long long oo = (o < 4194304LL) ? o : o - 4194304LL;
                const int4* p = (const int4*)(src + oo * 8);
                int4 v0 = p[0], v1 = p[1];
                unsigned bb = (unsigned)(v0.x & 1) | ((unsigned)(v0.y & 1) << 1) |
                              ((unsigned)(v0.z & 1) << 2) | ((unsigned)(v0.w & 1) << 3) |
                              ((unsigned)(v1.x & 1) << 4) | ((unsigned)(v1.y & 1) << 5) |
                              ((unsigned)(v1.z & 1) << 6) | ((unsigned)(v1.w & 1) << 7);
                cfgb[o] = (uint8_t)bb;
            }
        } else {
            // ---- wT hi/lo prep ----
            for (int idx = tid; idx < 8192; idx += 256) {
                int layer = idx >> 12, rem = idx & 4095, out = rem >> 6, in = rem & 63;
                float x = mlpW[layer * 4096 + in * 64 + out];
                short h, l2; hilo(x, h, l2);
                wbuf[layer * 8192 + out * 64 + in] = h;
                wbuf[layer * 8192 + 4096 + out * 64 + in] = l2;
            }
        }
        return;
    }

    // ---- literal path: 4 waves, one row per wave, 8 rows each, no barriers ----
    __shared__ float mid_ls[4][64];
    const int wv = tid >> 6, lane = tid & 63;
    for (int rr = 0; rr < 8; ++rr) {
        long long row = (long long)blockIdx.x * 32 + wv * 8 + rr;  // (g*32+b)*1024+n
        int g = (int)(row >> 15);
        long long nIdx = row & 32767;
        const float* lit  = g ? lit2  : lit1;
        const float* sem  = g ? sem2  : sem1;
        const float* Win  = g ? Win2  : Win1;
        const float* bin  = g ? bin2  : bin1;
        const float* Wout = g ? Wout2 : Wout1;
        const float* bout = g ? bout2 : bout1;
        const float* gk   = g ? gk2   : gk1;
        const float* gbp  = g ? gb2   : gb1;

        float acc = bin[lane];
        #pragma unroll
        for (int k = 0; k < LIT_; ++k) acc += lit[nIdx * LIT_ + k] * Win[k * E_ + lane];
        mid_ls[wv][lane] = fmaxf(acc, 0.f);

        if (lane < U_) {
            float a = bout[lane];
            #pragma unroll 8
            for (int k = 0; k < E_; ++k) a += mid_ls[wv][k] * Wout[k * U_ + lane];
            ebuf[row * E_ + lane] = fmaxf(a, 0.f);
        }
        {
            float a = gbp[lane];
            #pragma unroll
            for (int k = 0; k < SEM_; ++k) a += sem[nIdx * SEM_ + k] * gk[k * 96 + lane];
            xproj[row * 96 + lane] = a;
        }
        if (lane < 32) {
            int c = 64 + lane;
            float a2 = gbp[c];
            #pragma unroll
            for (int k = 0; k < SEM_; ++k) a2 += sem[nIdx * SEM_ + k] * gk[k * 96 + c];
            xproj[row * 96 + c] = a2;
        }
    }
}

// ---------- GRU recurrence: single wave per (g,b), barrier-free ----------
// fdot2 + scalar-pipe pair packing: h kept as f16 bits per lane; pairs built
// from two uniform readlanes via SALU shift/or (off the VALU issue & chain).
__global__ __launch_bounds__(64) void k_gru(
    const float* __restrict__ grk1, const float* __restrict__ gb1,
    const float* __restrict__ grk2, const float* __restrict__ gb2,
    const float* __restrict__ xproj, float* __restrict__ ebuf)
{
    const int gb_i = blockIdx.x;          // 0..63
    const int g = gb_i >> 5;
    const float* grk = g ? grk2 : grk1;
    const float* gbp = g ? gb2 : gb1;
    const int l = threadIdx.x;            // 0..63
    const int j = l & 31;

#if HAVE_FDOT2
    unsigned wzr[16], wh[16];             // packed f16 pairs (k even, k odd)
    #pragma unroll
    for (int k = 0; k < 16; ++k) {
        wzr[k] = pkrtz(grk[(2 * k) * 96 + l],       grk[(2 * k + 1) * 96 + l]);
        wh[k]  = pkrtz(grk[(2 * k) * 96 + 64 + j],  grk[(2 * k + 1) * 96 + 64 + j]);
    }
#else
    float wzr[32], wh[32];
    #pragma unroll
    for (int k = 0; k < 32; ++k) {
        wzr[k] = grk[k * 96 + l];
        wh[k]  = grk[k * 96 + 64 + j];
    }
#endif
    const float brec0 = gbp[96 + l];
    const float brec1 = gbp[96 + 64 + j];

    const float* xp = xproj + (long long)gb_i * N_ * 96;
    float* eb = ebuf + (long long)gb_i * N_ * E_ + 32;

    float h = 0.f;                        // per-lane h (valid lanes<32)
#if HAVE_FDOT2
    unsigned h16 = 0u;                    // f16 bits of h (low 16), valid lanes<32
#endif

    auto STEP = [&](float X0, float X1, int T) {
        float a0 = brec0, a1 = 0.f, a2 = 0.f, a3 = 0.f;
        float b0 = brec1, b1 = 0.f, b2 = 0.f, b3 = 0.f;
#if HAVE_FDOT2
        #pragma unroll
        for (int k = 0; k < 16; k += 4) {
            // two uniform readlanes per pair; pack on the scalar pipe
            unsigned p0 = (unsigned)__builtin_amdgcn_readlane((int)h16, 2 * k)
                        | ((unsigned)__builtin_amdgcn_readlane((int)h16, 2 * k + 1) << 16);
            unsigned p1 = (unsigned)__builtin_amdgcn_readlane((int)h16, 2 * k + 2)
                        | ((unsigned)__builtin_amdgcn_readlane((int)h16, 2 * k + 3) << 16);
            unsigned p2 = (unsigned)__builtin_amdgcn_readlane((int)h16, 2 * k + 4)
                        | ((unsigned)__builtin_amdgcn_readlane((int)h16, 2 * k + 5) << 16);
            unsigned p3 = (unsigned)__builtin_amdgcn_readlane((int)h16, 2 * k + 6)
                        | ((unsigned)__builtin_amdgcn_readlane((int)h16, 2 * k + 7) << 16);
            a0 = __builtin_amdgcn_fdot2(u2h(p0), u2h(wzr[k]),     a0, false);
            b0 = __builtin_amdgcn_fdot2(u2h(p0), u2h(wh[k]),      b0, false);
            a1 = __builtin_amdgcn_fdot2(u2h(p1), u2h(wzr[k + 1]), a1, false);
            b1 = __builtin_amdgcn_fdot2(u2h(p1), u2h(wh[k + 1]),  b1, false);
            a2 = __builtin_amdgcn_fdot2(u2h(p2), u2h(wzr[k + 2]), a2, false);
            b2 = __builtin_amdgcn_fdot2(u2h(p2), u2h(wh[k + 2]),  b2, false);
            a3 = __builtin_amdgcn_fdot2(u2h(p3), u2h(wzr[k + 3]), a3, false);
            b3 = __builtin_amdgcn_fdot2(u2h(p3), u2h(wh[k + 3]),  b3, false);
        }
#else
        #pragma unroll
        for (int k = 0; k < 32; k += 4) {
            float h0 = rdlane(h, k);
            float h1 = rdlane(h, k + 1);
            float h2 = rdlane(h, k + 2);
            float h3 = rdlane(h, k + 3);
            a0 = fmaf(h0, wzr[k],     a0);  b0 = fmaf(h0, wh[k],     b0);
            a1 = fmaf(h1, wzr[k + 1], a1);  b1 = fmaf(h1, wh[k + 1], b1);
            a2 = fmaf(h2, wzr[k + 2], a2);  b2 = fmaf(h2, wh[k + 2], b2);
            a3 = fmaf(h3, wzr[k + 3], a3);  b3 = fmaf(h3, wh[k + 3], b3);
        }
#endif
        float rec0 = (a0 + a1) + (a2 + a3);   // rec[l]      (z | r)
        float rec1 = (b0 + b1) + (b2 + b3);   // rec[64+j]   (h-col)
        float s = 1.f / (1.f + __expf(-(X0 + rec0)));  // z (lanes<32) | r (lanes>=32)
        float rv = __shfl(s, j + 32);         // r_j everywhere
        float zv = s;                         // z_j valid lanes<32 (upper half unused)
        float y  = X1 + rv * rec1;
        float e2 = __expf(2.f * y);
        float hh = 1.f - 2.f / (e2 + 1.f);
        float hn = hh + zv * (h - hh);
        h = hn;                               // valid lanes<32 only
        if (l < 32) eb[(long long)(T) * E_ + l] = fmaxf(hn, 0.f);
#if HAVE_FDOT2
        h16 = pkrtz(hn, 0.f);                 // f16 bits in low half (1 VALU on chain)
#endif
    };

    float x0a = xp[l],       x1a = xp[64 + j];
    float x0b = xp[96 + l],  x1b = xp[96 + 64 + j];

    for (int t = 0; t < N_; t += 2) {
        float nx0a = xp[(long long)(t + 2) * 96 + l];
        float nx1a = xp[(long long)(t + 2) * 96 + 64 + j];
        float nx0b = xp[(long long)(t + 3) * 96 + l];
        float nx1b = xp[(long long)(t + 3) * 96 + 64 + j];
        STEP(x0a, x1a, t);
        STEP(x0b, x1b, t + 1);
        x0a = nx0a; x1a = nx1a; x0b = nx0b; x1b = nx1b;
    }
}

// ---------- e (fp32, row-major) -> eT (bf16 hi only, [gb][64][1024]) ----------
__global__ __launch_bounds__(256) void k_etr(const float* __restrict__ ebuf,
                                             short* __restrict__ eTh)
{
    __shared__ float tls[128][68];
    const int blk = blockIdx.x, gb = blk >> 3, n0 = (blk & 7) * 128;
    const int tid = threadIdx.x;
    const float4* src = (const float4*)(ebuf + ((size_t)gb * N_ + n0) * E_);
    #pragma unroll
    for (int i = 0; i < 8; ++i) {
        int idx = tid + 256 * i;
        float4 v = src[idx];
        int row = idx >> 4, c4 = (idx & 15) << 2;
        tls[row][c4] = v.x; tls[row][c4 + 1] = v.y;
        tls[row][c4 + 2] = v.z; tls[row][c4 + 3] = v.w;
    }
    __syncthreads();
    const int w = tid >> 6, l = tid & 63;
    short* dh = eTh + ((size_t)gb << 16) + (size_t)l * 1024 + n0 + w * 32;
    #pragma unroll
    for (int ch = 0; ch < 4; ++ch) {
        s16x8 vh;
        #pragma unroll
        for (int i = 0; i < 8; ++i)
            vh[i] = (short)bf16rne(tls[w * 32 + ch * 8 + i][l]);
        *(s16x8*)(dh + ch * 8) = vh;
    }
}

// ---------- fused message passing (hi-only) + 2-layer MLP + tanh residual ----------
template<int WET>
__global__ __launch_bounds__(256, 3) void k_msgmlp(
    const uint8_t* __restrict__ cfgb,
    const short* __restrict__ eThS, short* __restrict__ eThD,
    float* __restrict__ ebuf,
    const short* __restrict__ wbuf, const float* __restrict__ mlpb)
{
    __shared__ float tls[128][66];
    __shared__ uint32_t cls[128][36];
    const int blk = blockIdx.x, gb = blk >> 3, n0 = (blk & 7) * 128;
    const int tid = threadIdx.x, w = tid >> 6, l = tid & 63;
    const int lr = l & 15, lk8 = (l >> 4) * 8;
    const int rh = w & 1, ch = w >> 1;

    {
        const uint4* srcv = (const uint4*)(cfgb + ((size_t)gb << 17) + (size_t)n0 * 128);
        #pragma unroll
        for (int i = 0; i < 4; ++i) {
            int idx = tid + 256 * i;
            uint4 v = srcv[idx];
            int base = idx * 4;
            int row = base >> 5, col = base & 31;
            *(uint4*)&cls[row][col] = v;
        }
    }
    __syncthreads();

    const short* bh = eThS + ((size_t)gb << 16) + (size_t)(ch * 32 + lr) * 1024 + lk8;

    f32x4 acc[4][2];
    #pragma unroll
    for (int rt = 0; rt < 4; ++rt)
        #pragma unroll
        for (int ct = 0; ct < 2; ++ct)
            acc[rt][ct] = (f32x4){0.f, 0.f, 0.f, 0.f};

    #pragma unroll 2
    for (int kk = 0; kk < 1024; kk += 32) {
        s16x8 vh0 = *(const s16x8*)(bh + kk);
        s16x8 vh1 = *(const s16x8*)(bh + 16384 + kk);
        #pragma unroll
        for (int rt = 0; rt < 4; ++rt) {
            unsigned dw = cls[rh * 64 + rt * 16 + lr][kk >> 5];
            unsigned t = dw >> lk8;
            union { s16x8 v; unsigned d[4]; } A;
            A.d[0] = ((t & 1u)        * 0x3F80u) | (((t >> 1) & 1u) * 0x3F800000u);
            A.d[1] = (((t >> 2) & 1u) * 0x3F80u) | (((t >> 3) & 1u) * 0x3F800000u);
            A.d[2] = (((t >> 4) & 1u) * 0x3F80u) | (((t >> 5) & 1u) * 0x3F800000u);
            A.d[3] = (((t >> 6) & 1u) * 0x3F80u) | (((t >> 7) & 1u) * 0x3F800000u);
            acc[rt][0] = MFMA_BF16(A.v, vh0, acc[rt][0]);
            acc[rt][1] = MFMA_BF16(A.v, vh1, acc[rt][1]);
        }
    }

    // t -> LDS (crosses waves) then barrier
    #pragma unroll
    for (int rt = 0; rt < 4; ++rt)
        #pragma unroll
        for (int ct = 0; ct < 2; ++ct)
            #pragma unroll
            for (int r = 0; r < 4; ++r)
                tls[rh * 64 + rt * 16 + (l >> 4) * 4 + r][ch * 32 + ct * 16 + lr] = acc[rt][ct][r];
    __syncthreads();

    float b0c[4], b1c[4];
    #pragma unroll
    for (int nt = 0; nt < 4; ++nt) {
        b0c[nt] = mlpb[nt * 16 + lr];
        b1c[nt] = mlpb[64 + nt * 16 + lr];
    }

    // ================= layer 1 (wave-local rows w*32..w*32+31) =================
    s16x8 ah[2][2], al[2][2];
    #pragma unroll
    for (int mt = 0; mt < 2; ++mt)
        #pragma unroll
        for (int kt = 0; kt < 2; ++kt) {
            const float* p = &tls[w * 32 + mt * 16 + lr][kt * 32 + lk8];
            #pragma unroll
            for (int i = 0; i < 8; ++i) { short hh, ll; hilo(p[i], hh, ll); ah[mt][kt][i] = hh; al[mt][kt][i] = ll; }
        }
    {
        f32x4 acc1[2][4];
        #pragma unroll
        for (int mt = 0; mt < 2; ++mt)
            #pragma unroll
            for (int nt = 0; nt < 4; ++nt)
                acc1[mt][nt] = (f32x4){b0c[nt], b0c[nt], b0c[nt], b0c[nt]};
        #pragma unroll
        for (int nt = 0; nt < 4; ++nt)
            #pragma unroll
            for (int kt = 0; kt < 2; ++kt) {
                s16x8 wth = *(const s16x8*)(wbuf + (nt * 16 + lr) * 64 + kt * 32 + lk8);
                s16x8 wtl = *(const s16x8*)(wbuf + 4096 + (nt * 16 + lr) * 64 + kt * 32 + lk8);
                #pragma unroll
                for (int mt = 0; mt < 2; ++mt) {
                    acc1[mt][nt] = MFMA_BF16(ah[mt][kt], wth, acc1[mt][nt]);
                    acc1[mt][nt] = MFMA_BF16(ah[mt][kt], wtl, acc1[mt][nt]);
                    acc1[mt][nt] = MFMA_BF16(al[mt][kt], wth, acc1[mt][nt]);
                }
            }
        __syncthreads();
        #pragma unroll
        for (int mt = 0; mt < 2; ++mt)
            #pragma unroll
            for (int nt = 0; nt < 4; ++nt)
                #pragma unroll
                for (int r = 0; r < 4; ++r)
                    tls[w * 32 + mt * 16 + (l >> 4) * 4 + r][nt * 16 + lr] = fmaxf(acc1[mt][nt][r], 0.f);
    }

    // ================= layer 2 =================
    #pragma unroll
    for (int mt = 0; mt < 2; ++mt)
        #pragma unroll
        for (int kt = 0; kt < 2; ++kt) {
            const float* p = &tls[w * 32 + mt * 16 + lr][kt * 32 + lk8];
            #pragma unroll
            for (int i = 0; i < 8; ++i) { short hh, ll; hilo(p[i], hh, ll); ah[mt][kt][i] = hh; al[mt][kt][i] = ll; }
        }
    f32x4 acc2[2][4];
    #pragma unroll
    for (int mt = 0; mt < 2; ++mt)
        #pragma unroll
        for (int nt = 0; nt < 4; ++nt)
            acc2[mt][nt] = (f32x4){b1c[nt], b1c[nt], b1c[nt], b1c[nt]};
    #pragma unroll
    for (int nt = 0; nt < 4; ++nt)
        #pragma unroll
        for (int kt = 0; kt < 2; ++kt) {
            s16x8 wth = *(const s16x8*)(wbuf + 8192 + (nt * 16 + lr) * 64 + kt * 32 + lk8);
            s16x8 wtl = *(const s16x8*)(wbuf + 8192 + 4096 + (nt * 16 + lr) * 64 + kt * 32 + lk8);
            #pragma unroll
            for (int mt = 0; mt < 2; ++mt) {
                acc2[mt][nt] = MFMA_BF16(ah[mt][kt], wth, acc2[mt][nt]);
                acc2[mt][nt] = MFMA_BF16(ah[mt][kt], wtl, acc2[mt][nt]);
                acc2[mt][nt] = MFMA_BF16(al[mt][kt], wth, acc2[mt][nt]);
            }
        }

    // e_new = tanh(e_old + relu(acc2))
    float* eb = ebuf + ((size_t)gb * N_ + n0) * E_;
    #pragma unroll
    for (int mt = 0; mt < 2; ++mt)
        #pragma unroll
        for (int nt = 0; nt < 4; ++nt)
            #pragma unroll
            for (int r = 0; r < 4; ++r) {
                int row = w * 32 + mt * 16 + (l >> 4) * 4 + r;
                int colq = nt * 16 + lr;
                float t2 = fmaxf(acc2[mt][nt][r], 0.f);
                float y = eb[(size_t)row * E_ + colq] + t2;
                float e2 = __expf(2.f * y);
                float en = 1.f - 2.f / (e2 + 1.f);
                eb[(size_t)row * E_ + colq] = en;
                if (WET) tls[row][colq] = en;
            }

    if (WET) {
        short* dh = eThD + ((size_t)gb << 16) + (size_t)l * 1024 + n0 + w * 32;
        #pragma unroll
        for (int chq = 0; chq < 4; ++chq) {
            s16x8 vh;
            #pragma unroll
            for (int i = 0; i < 8; ++i)
                vh[i] = (short)bf16rne(tls[w * 32 + chq * 8 + i][l]);
            *(s16x8*)(dh + chq * 8) = vh;
        }
    }
}

// ---------- node-sum partials ----------
__global__ __launch_bounds__(256) void k_outp(const float* __restrict__ ebuf,
                                              float* __restrict__ part)
{
    const int gb = blockIdx.x >> 2, ch = blockIdx.x & 3;
    const int col = threadIdx.x & 63, r0 = threadIdx.x >> 6;
    const float* eb = ebuf + ((size_t)gb * N_ + ch * 256) * E_;
    float s = 0.f;
    #pragma unroll 8
    for (int i = 0; i < 64; ++i) s += eb[(size_t)(r0 + i * 4) * E_ + col];
    __shared__ float sm[4][64];
    sm[r0][col] = s;
    __syncthreads();
    if (threadIdx.x < 64)
        part[(gb * 4 + ch) * 64 + threadIdx.x] =
            sm[0][threadIdx.x] + sm[1][threadIdx.x] + sm[2][threadIdx.x] + sm[3][threadIdx.x];
}

// ---------- final: sum partials, project, cosine ----------
__global__ __launch_bounds__(64) void k_fin(const float* __restrict__ part,
                                            const float* __restrict__ wOut,
                                            const float* __restrict__ bOut,
                                            float* __restrict__ dout)
{
    const int b = blockIdx.x, d = threadIdx.x;
    __shared__ float m1[64], m2[64];
    m1[d] = part[(b * 4 + 0) * 64 + d] + part[(b * 4 + 1) * 64 + d] +
            part[(b * 4 + 2) * 64 + d] + part[(b * 4 + 3) * 64 + d];
    m2[d] = part[((32 + b) * 4 + 0) * 64 + d] + part[((32 + b) * 4 + 1) * 64 + d] +
            part[((32 + b) * 4 + 2) * 64 + d] + part[((32 + b) * 4 + 3) * 64 + d];
    __syncthreads();
    float a1 = bOut[d], a2 = bOut[d];
    #pragma unroll 8
    for (int k = 0; k < 64; ++k) {
        a1 += m1[k] * wOut[k * 64 + d];
        a2 += m2[k] * wOut[k * 64 + d];
    }
    float s1 = a1 * a1, s2 = a2 * a2, s3 = a1 * a2;
    #pragma unroll
    for (int m = 32; m > 0; m >>= 1) {
        s1 += __shfl_xor(s1, m);
        s2 += __shfl_xor(s2, m);
        s3 += __shfl_xor(s3, m);
    }
    if (d == 0) {
        float n1 = sqrtf(fmaxf(s1, 1e-12f));
        float n2 = sqrtf(fmaxf(s2, 1e-12f));
        dout[b] = 0.5f * (s3 / (n1 * n2) + 1.0f);
    }
}

// ---------- fp32 fallback kernels ----------
__global__ __launch_bounds__(256) void k_msg_fb(
    const int* __restrict__ cfgi1, const int* __restrict__ cfgi2,
    const float* __restrict__ ebuf, float* __restrict__ tbuf)
{
    __shared__ float cfgf[128][65];
    __shared__ float els[64][64];
    const int blk = blockIdx.x;
    const int gb_i = blk >> 3;
    const int rg = blk & 7;
    const int g = gb_i >> 5;
    const int b = gb_i & 31;
    const int n0 = rg * 128;
    const int tid = threadIdx.x;
    const int tx = tid & 7, ty = tid >> 3;

    float acc[4][8];
    #pragma unroll
    for (int i = 0; i < 4; ++i)
        #pragma unroll
        for (int c = 0; c < 8; ++c) acc[i][c] = 0.f;

    const float* ebase = ebuf + (long long)gb_i * N_ * E_;
    const int row = tid >> 1, half = tid & 1;

    for (int m0 = 0; m0 < N_; m0 += 64) {
        {
            const float4* src = (const float4*)(ebase + (long long)m0 * E_);
            float4* dst = (float4*)(&els[0][0]);
            #pragma unroll
            for (int k = 0; k < 4; ++k) dst[tid + 256 * k] = src[tid + 256 * k];
        }
        {
            const int* cp = (g ? cfgi2 : cfgi1) + ((long long)b * N_ + n0 + row) * N_ + m0 + half * 32;
            #pragma unroll
            for (int q = 0; q < 8; ++q) {
                int4 v = ((const int4*)cp)[q];
                cfgf[row][half * 32 + q * 4 + 0] = (float)v.x;
                cfgf[row][half * 32 + q * 4 + 1] = (float)v.y;
                cfgf[row][half * 32 + q * 4 + 2] = (float)v.z;
                cfgf[row][half * 32 + q * 4 + 3] = (float)v.w;
            }
        }
        __syncthreads();

        #pragma unroll 4
        for (int mm = 0; mm < 64; ++mm) {
            float4 e0 = *(const float4*)&els[mm][tx * 8];
            float4 e1 = *(const float4*)&els[mm][tx * 8 + 4];
            #pragma unroll
            for (int i = 0; i < 4; ++i) {
                float c = cfgf[ty + 32 * i][mm];
                acc[i][0] += c * e0.x; acc[i][1] += c * e0.y;
                acc[i][2] += c * e0.z; acc[i][3] += c * e0.w;
                acc[i][4] += c * e1.x; acc[i][5] += c * e1.y;
                acc[i][6] += c * e1.z; acc[i][7] += c * e1.w;
            }
        }
        __syncthreads();
    }

    float* tb = tbuf + (long long)gb_i * N_ * E_;
    #pragma unroll
    for (int i = 0; i < 4; ++i) {
        int r = n0 + ty + 32 * i;
        float4 o0 = {acc[i][0], acc[i][1], acc[i][2], acc[i][3]};
        float4 o1 = {acc[i][4], acc[i][5], acc[i][6], acc[i][7]};
        *(float4*)&tb[(long long)r * E_ + tx * 8] = o0;
        *(float4*)&tb[(long long)r * E_ + tx * 8 + 4] = o1;
    }
}

__global__ __launch_bounds__(64) void k_mlp_fb(
    const float* __restrict__ tbuf, float* __restrict__ ebuf,
    const float* __restrict__ mlpW, const float* __restrict__ mlpb)
{
    __shared__ float tls[64][65];
    __shared__ float mls[64][65];
    const int tid = threadIdx.x;
    const long long r0 = (long long)blockIdx.x * 64;

    {
        const float4* src = (const float4*)(tbuf + r0 * E_);
        #pragma unroll
        for (int i = 0; i < 16; ++i) {
            int f4 = tid + 64 * i;
            float4 v = src[f4];
            int row = f4 >> 4, col = (f4 & 15) << 2;
            tls[row][col] = v.x; tls[row][col + 1] = v.y;
            tls[row][col + 2] = v.z; tls[row][col + 3] = v.w;
        }
    }
    __syncthreads();

    for (int dc = 0; dc < 8; ++dc) {
        float a[8];
        #pragma unroll
        for (int c = 0; c < 8; ++c) a[c] = mlpb[dc * 8 + c];
        #pragma unroll 8
        for (int k = 0; k < 64; ++k) {
            float tv = tls[tid][k];
            #pragma unroll
            for (int c = 0; c < 8; ++c) a[c] += tv * mlpW[k * 64 + dc * 8 + c];
        }
        #pragma unroll
        for (int c = 0; c < 8; ++c) mls[tid][dc * 8 + c] = fmaxf(a[c], 0.f);
    }
    for (int dc = 0; dc < 8; ++dc) {
        float a[8];
        #pragma unroll
        for (int c = 0; c < 8; ++c) a[c] = mlpb[64 + dc * 8 + c];
        #pragma unroll 8
        for (int k = 0; k < 64; ++k) {
            float tv = mls[tid][k];
            #pragma unroll
            for (int c = 0; c < 8; ++c) a[c] += tv * mlpW[4096 + k * 64 + dc * 8 + c];
        }
        #pragma unroll
        for (int c = 0; c < 8; ++c) tls[tid][dc * 8 + c] = fmaxf(a[c], 0.f);
    }
    __syncthreads();

    {
        float4* eb = (float4*)(ebuf + r0 * E_);
        #pragma unroll
        for (int i = 0; i < 16; ++i) {
            int f4 = tid + 64 * i;
            int row = f4 >> 4, col = (f4 & 15) << 2;
            float4 ev = eb[f4];
            float4 o;
            o.x = tanhf(ev.x + tls[row][col]);
            o.y = tanhf(ev.y + tls[row][col + 1]);
            o.z = tanhf(ev.z + tls[row][col + 2]);
            o.w = tanhf(ev.w + tls[row][col + 3]);
            eb[f4] = o;
        }
    }
}

__global__ __launch_bounds__(64) void k_out(const float* __restrict__ ebuf,
                                            const float* __restrict__ wOut,
                                            const float* __restrict__ bOut,
                                            float* __restrict__ outws)
{
    __shared__ float mid[E_];
    const int gb_i = blockIdx.x;
    const int tid = threadIdx.x;
    const float* eb = ebuf + (long long)gb_i * N_ * E_;
    float s = 0.f;
    for (int n = 0; n < N_; ++n) s += eb[(long long)n * E_ + tid];
    mid[tid] = s;
    __syncthreads();
    float a = bOut[tid];
    #pragma unroll 8
    for (int k = 0; k < E_; ++k) a += mid[k] * wOut[k * E_ + tid];
    outws[gb_i * E_ + tid] = a;
}

__global__ __launch_bounds__(64) void k_cos(const float* __restrict__ outws,
                                            float* __restrict__ dout)
{
    const int b = blockIdx.x, d = threadIdx.x;
    float a = outws[b * E_ + d];
    float c = outws[(32 + b) * E_ + d];
    float s1 = a * a, s2 = c * c, s3 = a * c;
    #pragma unroll
    for (int m = 32; m > 0; m >>= 1) {
        s1 += __shfl_xor(s1, m);
        s2 += __shfl_xor(s2, m);
        s3 += __shfl_xor(s3, m);
    }
    if (d == 0) {
        float n1 = sqrtf(fmaxf(s1, 1e-12f));
        float n2 = sqrtf(fmaxf(s2, 1e-12f));
        dout[b] = 0.5f * (s3 / (n1 * n2) + 1.0f);
    }
}

extern "C" void kernel_launch(void* const* d_in, const int* in_sizes, int n_in,
                              void* d_out, int out_size, void* d_ws, size_t ws_size,
                              hipStream_t stream) {
    const int*   CFG1 = (const int*)d_in[0];
    const float* LIT1 = (const float*)d_in[2];
    const float* SEM1 = (const float*)d_in[3];
    const int*   CFG2 = (const int*)d_in[4];
    const float* LIT2 = (const float*)d_in[6];
    const float* SEM2 = (const float*)d_in[7];
    const float* d1_Win  = (const float*)d_in[8];
    const float* d1_bin  = (const float*)d_in[9];
    const float* d1_Wout = (const float*)d_in[10];
    const float* d1_bout = (const float*)d_in[11];
    const float* d1_gk   = (const float*)d_in[12];
    const float* d1_grk  = (const float*)d_in[13];
    const float* d1_gb   = (const float*)d_in[14];
    const float* d2_Win  = (const float*)d_in[15];
    const float* d2_bin  = (const float*)d_in[16];
    const float* d2_Wout = (const float*)d_in[17];
    const float* d2_bout = (const float*)d_in[18];
    const float* d2_gk   = (const float*)d_in[19];
    const float* d2_grk  = (const float*)d_in[20];
    const float* d2_gb   = (const float*)d_in[21];
    const float* mlpW = (const float*)d_in[22];
    const float* mlpb = (const float*)d_in[23];
    const float* wOut = (const float*)d_in[24];
    const float* bOut = (const float*)d_in[25];

    char* ws = (char*)d_ws;

    if (ws_size >= F_MIN) {
        float*   xproj = (float*)(ws + 0);            // phase-1 overlay
        short*   eT0h  = (short*)(ws + F_ET0H);
        short*   eT1h  = (short*)(ws + F_ET1H);
        float*   ebuf  = (float*)(ws + F_EBUF);
        uint8_t* cfgb  = (uint8_t*)(ws + F_CFGB);
        short*   wbuf  = (short*)(ws + F_WBUF);
        float*   part  = (float*)(ws + F_ET1L);

        k_pre<<<LITBLK + 4097, 256, 0, stream>>>(LIT1, SEM1, LIT2, SEM2,
                                                 d1_Win, d1_bin, d1_Wout, d1_bout, d1_gk, d1_gb,
                                                 d2_Win, d2_bin, d2_Wout, d2_bout, d2_gk, d2_gb,
                                                 ebuf, xproj, CFG1, CFG2, cfgb, mlpW, wbuf);

        k_gru<<<64, 64, 0, stream>>>(d1_grk, d1_gb, d2_grk, d2_gb, xproj, ebuf);

        k_etr<<<512, 256, 0, stream>>>(ebuf, eT0h);

        for (int it = 0; it < 5; ++it) {
            short* sh = (it & 1) ? eT1h : eT0h;
            short* dh = (it & 1) ? eT0h : eT1h;
            if (it < 4)
                k_msgmlp<1><<<512, 256, 0, stream>>>(cfgb, sh, dh, ebuf, wbuf, mlpb);
            else
                k_msgmlp<0><<<512, 256, 0, stream>>>(cfgb, sh, dh, ebuf, wbuf, mlpb);
        }

        k_outp<<<256, 256, 0, stream>>>(ebuf, part);
        k_fin<<<32, 64, 0, stream>>>(part, wOut, bOut, (float*)d_out);
    } else if (ws_size >= O_MIN) {
        float* xproj = (float*)(ws + O_XPROJ);
        float* tbuf  = (float*)(ws + O_T);
        float* ebuf  = (float*)(ws + O_E);
        float* outws = (float*)(ws + O_OW);

        k_pre<<<LITBLK, 256, 0, stream>>>(LIT1, SEM1, LIT2, SEM2,
                                          d1_Win, d1_bin, d1_Wout, d1_bout, d1_gk, d1_gb,
                                          d2_Win, d2_bin, d2_Wout, d2_bout, d2_gk, d2_gb,
                                          ebuf, xproj, CFG1, CFG2, (uint8_t*)ws, mlpW, (short*)ws);

        k_gru<<<64, 64, 0, stream>>>(d1_grk, d1_gb, d2_grk, d2_gb, xproj, ebuf);

        for (int it = 0; it < 5; ++it) {
            k_msg_fb<<<512, 256, 0, stream>>>(CFG1, CFG2, ebuf, tbuf);
            k_mlp_fb<<<1024, 64, 0, stream>>>(tbuf, ebuf, mlpW, mlpb);
        }

        k_out<<<GBN, 64, 0, stream>>>(ebuf, wOut, bOut, outws);
        k_cos<<<32, 64, 0, stream>>>(outws, (float*)d_out);
    }
}

// Round 17
// 589.947 us; speedup vs baseline: 1.4569x; 1.4569x over previous
//
#include <hip/hip_runtime.h>
#include <stdint.h>
#include <math.h>

#define B_   32
#define N_   1024
#define U_   32
#define E_   64
#define LIT_ 12
#define SEM_ 16
#define GBN  64   // 2 graphs * 32 batch

typedef float f32x4 __attribute__((ext_vector_type(4)));
typedef short s16x8 __attribute__((ext_vector_type(8)));
typedef __fp16 h16x2 __attribute__((ext_vector_type(2)));
#define MFMA_BF16(a,b,c) __builtin_amdgcn_mfma_f32_16x16x32_bf16(a,b,c,0,0,0)

#if __has_builtin(__builtin_amdgcn_fdot2)
#define HAVE_FDOT2 1
#else
#define HAVE_FDOT2 0
#endif

// ---------------- primary (bit-packed cfg) layout ----------------
#define F_ET0H 0ULL
#define F_ET1H 16777216ULL
#define F_ET1L 25165824ULL      // part
#define F_EBUF 33554432ULL
#define F_CFGB 50331648ULL      // 8388608 bit-packed cfg
#define F_WBUF 58720256ULL      // 32768 (wT hi/lo, 2 layers)
#define F_MIN  58753024ULL

// ---------------- fp32 fallback layout ----------------
#define O_XPROJ 0ULL
#define O_T     25165824ULL
#define O_E     41943040ULL
#define O_OW    58720256ULL
#define O_MIN   58736640ULL

#define LITBLK 2048             // literal blocks in k_pre (256 thr, 32 rows each)

__device__ __forceinline__ float rdlane(float v, int k) {
    return __int_as_float(__builtin_amdgcn_readlane(__float_as_int(v), k));
}
__device__ __forceinline__ unsigned short bf16rne(float x) {
    unsigned u = __float_as_uint(x);
    return (unsigned short)((u + 0x7FFFu + ((u >> 16) & 1u)) >> 16);
}
__device__ __forceinline__ void hilo(float x, short& h, short& l) {
    unsigned short hb = bf16rne(x);
    float hf = __uint_as_float(((unsigned)hb) << 16);
    h = (short)hb;
    l = (short)bf16rne(x - hf);
}
__device__ __forceinline__ unsigned pkrtz(float a, float b) {
    union { h16x2 h; unsigned u; } c;
    c.h = __builtin_amdgcn_cvt_pkrtz(a, b);
    return c.u;
}
__device__ __forceinline__ h16x2 u2h(unsigned u) {
    union { unsigned u; h16x2 h; } c; c.u = u; return c.h;
}

// ---------- k_pre: literal path (wave-per-row, barrier-free) + cfg bit-pack + W prep ----
__global__ __launch_bounds__(256) void k_pre(
    const float* __restrict__ lit1, const float* __restrict__ sem1,
    const float* __restrict__ lit2, const float* __restrict__ sem2,
    const float* __restrict__ Win1, const float* __restrict__ bin1,
    const float* __restrict__ Wout1, const float* __restrict__ bout1,
    const float* __restrict__ gk1, const float* __restrict__ gb1,
    const float* __restrict__ Win2, const float* __restrict__ bin2,
    const float* __restrict__ Wout2, const float* __restrict__ bout2,
    const float* __restrict__ gk2, const float* __restrict__ gb2,
    float* __restrict__ ebuf, float* __restrict__ xproj,
    const int* __restrict__ c1, const int* __restrict__ c2,
    uint8_t* __restrict__ cfgb,
    const float* __restrict__ mlpW, short* __restrict__ wbuf)
{
    const int tid = threadIdx.x;
    if (blockIdx.x >= LITBLK) {
        if (blockIdx.x <= LITBLK + 4095) {
            // ---- bit-pack cfg: 8 int32 -> 1 byte ----
            int g = blockIdx.x - LITBLK;               // 0..4095
            long long gt = (long long)g * 256 + tid;   // 0..1048575
            #pragma unroll 4
            for (int it = 0; it < 8; ++it) {
                long long o = gt + 1048576LL * it;     // byte index 0..8388607
                const int* src = (o < 4194304LL) ? c1 : c2;
                long long oo = (o < 4194304LL) ? o : o - 4194304LL;
                const int4* p = (const int4*)(src + oo * 8);
                int4 v0 = p[0], v1 = p[1];
                unsigned bb = (unsigned)(v0.x & 1) | ((unsigned)(v0.y & 1) << 1) |
                              ((unsigned)(v0.z & 1) << 2) | ((unsigned)(v0.w & 1) << 3) |
                              ((unsigned)(v1.x & 1) << 4) | ((unsigned)(v1.y & 1) << 5) |
                              ((unsigned)(v1.z & 1) << 6) | ((unsigned)(v1.w & 1) << 7);
                cfgb[o] = (uint8_t)bb;
            }
        } else {
            // ---- wT hi/lo prep ----
            for (int idx = tid; idx < 8192; idx += 256) {
                int layer = idx >> 12, rem = idx & 4095, out = rem >> 6, in = rem & 63;
                float x = mlpW[layer * 4096 + in * 64 + out];
                short h, l2; hilo(x, h, l2);
                wbuf[layer * 8192 + out * 64 + in] = h;
                wbuf[layer * 8192 + 4096 + out * 64 + in] = l2;
            }
        }
        return;
    }

    // ---- literal path: 4 waves, one row per wave, 8 rows each, no barriers ----
    __shared__ float mid_ls[4][64];
    const int wv = tid >> 6, lane = tid & 63;
    for (int rr = 0; rr < 8; ++rr) {
        long long row = (long long)blockIdx.x * 32 + wv * 8 + rr;  // (g*32+b)*1024+n
        int g = (int)(row >> 15);
        long long nIdx = row & 32767;
        const float* lit  = g ? lit2  : lit1;
        const float* sem  = g ? sem2  : sem1;
        const float* Win  = g ? Win2  : Win1;
        const float* bin  = g ? bin2  : bin1;
        const float* Wout = g ? Wout2 : Wout1;
        const float* bout = g ? bout2 : bout1;
        const float* gk   = g ? gk2   : gk1;
        const float* gbp  = g ? gb2   : gb1;

        float acc = bin[lane];
        #pragma unroll
        for (int k = 0; k < LIT_; ++k) acc += lit[nIdx * LIT_ + k] * Win[k * E_ + lane];
        mid_ls[wv][lane] = fmaxf(acc, 0.f);

        if (lane < U_) {
            float a = bout[lane];
            #pragma unroll 8
            for (int k = 0; k < E_; ++k) a += mid_ls[wv][k] * Wout[k * U_ + lane];
            ebuf[row * E_ + lane] = fmaxf(a, 0.f);
        }
        {
            float a = gbp[lane];
            #pragma unroll
            for (int k = 0; k < SEM_; ++k) a += sem[nIdx * SEM_ + k] * gk[k * 96 + lane];
            xproj[row * 96 + lane] = a;
        }
        if (lane < 32) {
            int c = 64 + lane;
            float a2 = gbp[c];
            #pragma unroll
            for (int k = 0; k < SEM_; ++k) a2 += sem[nIdx * SEM_ + k] * gk[k * 96 + c];
            xproj[row * 96 + c] = a2;
        }
    }
}

// ---------- GRU recurrence: single wave per (g,b), barrier-free (r14-proven 322us) ----------
// fdot2 path: h packed f16x2 (16 readlanes + 32 dot2); hp repacked via 2 shfl + pkrtz.
__global__ __launch_bounds__(64) void k_gru(
    const float* __restrict__ grk1, const float* __restrict__ gb1,
    const float* __restrict__ grk2, const float* __restrict__ gb2,
    const float* __restrict__ xproj, float* __restrict__ ebuf)
{
    const int gb_i = blockIdx.x;          // 0..63
    const int g = gb_i >> 5;
    const float* grk = g ? grk2 : grk1;
    const float* gbp = g ? gb2 : gb1;
    const int l = threadIdx.x;            // 0..63
    const int j = l & 31;

#if HAVE_FDOT2
    unsigned wzr[16], wh[16];             // packed f16 pairs (k even, k odd)
    #pragma unroll
    for (int k = 0; k < 16; ++k) {
        wzr[k] = pkrtz(grk[(2 * k) * 96 + l],       grk[(2 * k + 1) * 96 + l]);
        wh[k]  = pkrtz(grk[(2 * k) * 96 + 64 + j],  grk[(2 * k + 1) * 96 + 64 + j]);
    }
#else
    float wzr[32], wh[32];
    #pragma unroll
    for (int k = 0; k < 32; ++k) {
        wzr[k] = grk[k * 96 + l];
        wh[k]  = grk[k * 96 + 64 + j];
    }
#endif
    const float brec0 = gbp[96 + l];
    const float brec1 = gbp[96 + 64 + j];

    const float* xp = xproj + (long long)gb_i * N_ * 96;
    float* eb = ebuf + (long long)gb_i * N_ * E_ + 32;

    float h = 0.f;                        // per-lane h (valid lanes<32)
#if HAVE_FDOT2
    unsigned hp = 0u;                     // packed (h[2p],h[2p+1]) valid lanes 0..15
    const int pidx = (l & 15) * 2;
#endif

    auto STEP = [&](float X0, float X1, int T) {
        float a0 = brec0, a1 = 0.f, a2 = 0.f, a3 = 0.f;
        float b0 = brec1, b1 = 0.f, b2 = 0.f, b3 = 0.f;
#if HAVE_FDOT2
        #pragma unroll
        for (int k = 0; k < 16; k += 4) {
            unsigned p0 = (unsigned)__builtin_amdgcn_readlane((int)hp, k);
            unsigned p1 = (unsigned)__builtin_amdgcn_readlane((int)hp, k + 1);
            unsigned p2 = (unsigned)__builtin_amdgcn_readlane((int)hp, k + 2);
            unsigned p3 = (unsigned)__builtin_amdgcn_readlane((int)hp, k + 3);
            a0 = __builtin_amdgcn_fdot2(u2h(p0), u2h(wzr[k]),     a0, false);
            b0 = __builtin_amdgcn_fdot2(u2h(p0), u2h(wh[k]),      b0, false);
            a1 = __builtin_amdgcn_fdot2(u2h(p1), u2h(wzr[k + 1]), a1, false);
            b1 = __builtin_amdgcn_fdot2(u2h(p1), u2h(wh[k + 1]),  b1, false);
            a2 = __builtin_amdgcn_fdot2(u2h(p2), u2h(wzr[k + 2]), a2, false);
            b2 = __builtin_amdgcn_fdot2(u2h(p2), u2h(wh[k + 2]),  b2, false);
            a3 = __builtin_amdgcn_fdot2(u2h(p3), u2h(wzr[k + 3]), a3, false);
            b3 = __builtin_amdgcn_fdot2(u2h(p3), u2h(wh[k + 3]),  b3, false);
        }
#else
        #pragma unroll
        for (int k = 0; k < 32; k += 4) {
            float h0 = rdlane(h, k);
            float h1 = rdlane(h, k + 1);
            float h2 = rdlane(h, k + 2);
            float h3 = rdlane(h, k + 3);
            a0 = fmaf(h0, wzr[k],     a0);  b0 = fmaf(h0, wh[k],     b0);
            a1 = fmaf(h1, wzr[k + 1], a1);  b1 = fmaf(h1, wh[k + 1], b1);
            a2 = fmaf(h2, wzr[k + 2], a2);  b2 = fmaf(h2, wh[k + 2], b2);
            a3 = fmaf(h3, wzr[k + 3], a3);  b3 = fmaf(h3, wh[k + 3], b3);
        }
#endif
        float rec0 = (a0 + a1) + (a2 + a3);   // rec[l]      (z | r)
        float rec1 = (b0 + b1) + (b2 + b3);   // rec[64+j]   (h-col)
        float s = 1.f / (1.f + __expf(-(X0 + rec0)));  // z (lanes<32) | r (lanes>=32)
        float rv = __shfl(s, j + 32);         // r_j everywhere
        float zv = s;                         // z_j valid lanes<32 (upper half unused)
        float y  = X1 + rv * rec1;
        float e2 = __expf(2.f * y);
        float hh = 1.f - 2.f / (e2 + 1.f);
        float hn = hh + zv * (h - hh);
        h = hn;                               // valid lanes<32 only
        if (l < 32) eb[(long long)(T) * E_ + l] = fmaxf(hn, 0.f);
#if HAVE_FDOT2
        float ep0 = __shfl(hn, pidx);         // h[2p]
        float ep1 = __shfl(hn, pidx + 1);     // h[2p+1]
        hp = pkrtz(ep0, ep1);
#endif
    };

    float x0a = xp[l],       x1a = xp[64 + j];
    float x0b = xp[96 + l],  x1b = xp[96 + 64 + j];

    for (int t = 0; t < N_; t += 2) {
        float nx0a = xp[(long long)(t + 2) * 96 + l];
        float nx1a = xp[(long long)(t + 2) * 96 + 64 + j];
        float nx0b = xp[(long long)(t + 3) * 96 + l];
        float nx1b = xp[(long long)(t + 3) * 96 + 64 + j];
        STEP(x0a, x1a, t);
        STEP(x0b, x1b, t + 1);
        x0a = nx0a; x1a = nx1a; x0b = nx0b; x1b = nx1b;
    }
}

// ---------- e (fp32, row-major) -> eT (bf16 hi only, [gb][64][1024]) ----------
__global__ __launch_bounds__(256) void k_etr(const float* __restrict__ ebuf,
                                             short* __restrict__ eTh)
{
    __shared__ float tls[128][68];
    const int blk = blockIdx.x, gb = blk >> 3, n0 = (blk & 7) * 128;
    const int tid = threadIdx.x;
    const float4* src = (const float4*)(ebuf + ((size_t)gb * N_ + n0) * E_);
    #pragma unroll
    for (int i = 0; i < 8; ++i) {
        int idx = tid + 256 * i;
        float4 v = src[idx];
        int row = idx >> 4, c4 = (idx & 15) << 2;
        tls[row][c4] = v.x; tls[row][c4 + 1] = v.y;
        tls[row][c4 + 2] = v.z; tls[row][c4 + 3] = v.w;
    }
    __syncthreads();
    const int w = tid >> 6, l = tid & 63;
    short* dh = eTh + ((size_t)gb << 16) + (size_t)l * 1024 + n0 + w * 32;
    #pragma unroll
    for (int ch = 0; ch < 4; ++ch) {
        s16x8 vh;
        #pragma unroll
        for (int i = 0; i < 8; ++i)
            vh[i] = (short)bf16rne(tls[w * 32 + ch * 8 + i][l]);
        *(s16x8*)(dh + ch * 8) = vh;
    }
}

// ---------- fused message passing (hi-only) + 2-layer MLP + tanh residual ----------
template<int WET>
__global__ __launch_bounds__(256, 3) void k_msgmlp(
    const uint8_t* __restrict__ cfgb,
    const short* __restrict__ eThS, short* __restrict__ eThD,
    float* __restrict__ ebuf,
    const short* __restrict__ wbuf, const float* __restrict__ mlpb)
{
    __shared__ float tls[128][66];
    __shared__ uint32_t cls[128][36];
    const int blk = blockIdx.x, gb = blk >> 3, n0 = (blk & 7) * 128;
    const int tid = threadIdx.x, w = tid >> 6, l = tid & 63;
    const int lr = l & 15, lk8 = (l >> 4) * 8;
    const int rh = w & 1, ch = w >> 1;

    {
        const uint4* srcv = (const uint4*)(cfgb + ((size_t)gb << 17) + (size_t)n0 * 128);
        #pragma unroll
        for (int i = 0; i < 4; ++i) {
            int idx = tid + 256 * i;
            uint4 v = srcv[idx];
            int base = idx * 4;
            int row = base >> 5, col = base & 31;
            *(uint4*)&cls[row][col] = v;
        }
    }
    __syncthreads();

    const short* bh = eThS + ((size_t)gb << 16) + (size_t)(ch * 32 + lr) * 1024 + lk8;

    f32x4 acc[4][2];
    #pragma unroll
    for (int rt = 0; rt < 4; ++rt)
        #pragma unroll
        for (int ct = 0; ct < 2; ++ct)
            acc[rt][ct] = (f32x4){0.f, 0.f, 0.f, 0.f};

    #pragma unroll 2
    for (int kk = 0; kk < 1024; kk += 32) {
        s16x8 vh0 = *(const s16x8*)(bh + kk);
        s16x8 vh1 = *(const s16x8*)(bh + 16384 + kk);
        #pragma unroll
        for (int rt = 0; rt < 4; ++rt) {
            unsigned dw = cls[rh * 64 + rt * 16 + lr][kk >> 5];
            unsigned t = dw >> lk8;
            union { s16x8 v; unsigned d[4]; } A;
            A.d[0] = ((t & 1u)        * 0x3F80u) | (((t >> 1) & 1u) * 0x3F800000u);
            A.d[1] = (((t >> 2) & 1u) * 0x3F80u) | (((t >> 3) & 1u) * 0x3F800000u);
            A.d[2] = (((t >> 4) & 1u) * 0x3F80u) | (((t >> 5) & 1u) * 0x3F800000u);
            A.d[3] = (((t >> 6) & 1u) * 0x3F80u) | (((t >> 7) & 1u) * 0x3F800000u);
            acc[rt][0] = MFMA_BF16(A.v, vh0, acc[rt][0]);
            acc[rt][1] = MFMA_BF16(A.v, vh1, acc[rt][1]);
        }
    }

    // t -> LDS (crosses waves) then barrier
    #pragma unroll
    for (int rt = 0; rt < 4; ++rt)
        #pragma unroll
        for (int ct = 0; ct < 2; ++ct)
            #pragma unroll
            for (int r = 0; r < 4; ++r)
                tls[rh * 64 + rt * 16 + (l >> 4) * 4 + r][ch * 32 + ct * 16 + lr] = acc[rt][ct][r];
    __syncthreads();

    float b0c[4], b1c[4];
    #pragma unroll
    for (int nt = 0; nt < 4; ++nt) {
        b0c[nt] = mlpb[nt * 16 + lr];
        b1c[nt] = mlpb[64 + nt * 16 + lr];
    }

    // ================= layer 1 (wave-local rows w*32..w*32+31) =================
    s16x8 ah[2][2], al[2][2];
    #pragma unroll
    for (int mt = 0; mt < 2; ++mt)
        #pragma unroll
        for (int kt = 0; kt < 2; ++kt) {
            const float* p = &tls[w * 32 + mt * 16 + lr][kt * 32 + lk8];
            #pragma unroll
            for (int i = 0; i < 8; ++i) { short hh, ll; hilo(p[i], hh, ll); ah[mt][kt][i] = hh; al[mt][kt][i] = ll; }
        }
    {
        f32x4 acc1[2][4];
        #pragma unroll
        for (int mt = 0; mt < 2; ++mt)
            #pragma unroll
            for (int nt = 0; nt < 4; ++nt)
                acc1[mt][nt] = (f32x4){b0c[nt], b0c[nt], b0c[nt], b0c[nt]};
        #pragma unroll
        for (int nt = 0; nt < 4; ++nt)
            #pragma unroll
            for (int kt = 0; kt < 2; ++kt) {
                s16x8 wth = *(const s16x8*)(wbuf + (nt * 16 + lr) * 64 + kt * 32 + lk8);
                s16x8 wtl = *(const s16x8*)(wbuf + 4096 + (nt * 16 + lr) * 64 + kt * 32 + lk8);
                #pragma unroll
                for (int mt = 0; mt < 2; ++mt) {
                    acc1[mt][nt] = MFMA_BF16(ah[mt][kt], wth, acc1[mt][nt]);
                    acc1[mt][nt] = MFMA_BF16(ah[mt][kt], wtl, acc1[mt][nt]);
                    acc1[mt][nt] = MFMA_BF16(al[mt][kt], wth, acc1[mt][nt]);
                }
            }
        __syncthreads();
        #pragma unroll
        for (int mt = 0; mt < 2; ++mt)
            #pragma unroll
            for (int nt = 0; nt < 4; ++nt)
                #pragma unroll
                for (int r = 0; r < 4; ++r)
                    tls[w * 32 + mt * 16 + (l >> 4) * 4 + r][nt * 16 + lr] = fmaxf(acc1[mt][nt][r], 0.f);
    }

    // ================= layer 2 =================
    #pragma unroll
    for (int mt = 0; mt < 2; ++mt)
        #pragma unroll
        for (int kt = 0; kt < 2; ++kt) {
            const float* p = &tls[w * 32 + mt * 16 + lr][kt * 32 + lk8];
            #pragma unroll
            for (int i = 0; i < 8; ++i) { short hh, ll; hilo(p[i], hh, ll); ah[mt][kt][i] = hh; al[mt][kt][i] = ll; }
        }
    f32x4 acc2[2][4];
    #pragma unroll
    for (int mt = 0; mt < 2; ++mt)
        #pragma unroll
        for (int nt = 0; nt < 4; ++nt)
            acc2[mt][nt] = (f32x4){b1c[nt], b1c[nt], b1c[nt], b1c[nt]};
    #pragma unroll
    for (int nt = 0; nt < 4; ++nt)
        #pragma unroll
        for (int kt = 0; kt < 2; ++kt) {
            s16x8 wth = *(const s16x8*)(wbuf + 8192 + (nt * 16 + lr) * 64 + kt * 32 + lk8);
            s16x8 wtl = *(const s16x8*)(wbuf + 8192 + 4096 + (nt * 16 + lr) * 64 + kt * 32 + lk8);
            #pragma unroll
            for (int mt = 0; mt < 2; ++mt) {
                acc2[mt][nt] = MFMA_BF16(ah[mt][kt], wth, acc2[mt][nt]);
                acc2[mt][nt] = MFMA_BF16(ah[mt][kt], wtl, acc2[mt][nt]);
                acc2[mt][nt] = MFMA_BF16(al[mt][kt], wth, acc2[mt][nt]);
            }
        }

    // e_new = tanh(e_old + relu(acc2))
    float* eb = ebuf + ((size_t)gb * N_ + n0) * E_;
    #pragma unroll
    for (int mt = 0; mt < 2; ++mt)
        #pragma unroll
        for (int nt = 0; nt < 4; ++nt)
            #pragma unroll
            for (int r = 0; r < 4; ++r) {
                int row = w * 32 + mt * 16 + (l >> 4) * 4 + r;
                int colq = nt * 16 + lr;
                float t2 = fmaxf(acc2[mt][nt][r], 0.f);
                float y = eb[(size_t)row * E_ + colq] + t2;
                float e2 = __expf(2.f * y);
                float en = 1.f - 2.f / (e2 + 1.f);
                eb[(size_t)row * E_ + colq] = en;
                if (WET) tls[row][colq] = en;
            }

    if (WET) {
        short* dh = eThD + ((size_t)gb << 16) + (size_t)l * 1024 + n0 + w * 32;
        #pragma unroll
        for (int chq = 0; chq < 4; ++chq) {
            s16x8 vh;
            #pragma unroll
            for (int i = 0; i < 8; ++i)
                vh[i] = (short)bf16rne(tls[w * 32 + chq * 8 + i][l]);
            *(s16x8*)(dh + chq * 8) = vh;
        }
    }
}

// ---------- node-sum partials ----------
__global__ __launch_bounds__(256) void k_outp(const float* __restrict__ ebuf,
                                              float* __restrict__ part)
{
    const int gb = blockIdx.x >> 2, ch = blockIdx.x & 3;
    const int col = threadIdx.x & 63, r0 = threadIdx.x >> 6;
    const float* eb = ebuf + ((size_t)gb * N_ + ch * 256) * E_;
    float s = 0.f;
    #pragma unroll 8
    for (int i = 0; i < 64; ++i) s += eb[(size_t)(r0 + i * 4) * E_ + col];
    __shared__ float sm[4][64];
    sm[r0][col] = s;
    __syncthreads();
    if (threadIdx.x < 64)
        part[(gb * 4 + ch) * 64 + threadIdx.x] =
            sm[0][threadIdx.x] + sm[1][threadIdx.x] + sm[2][threadIdx.x] + sm[3][threadIdx.x];
}

// ---------- final: sum partials, project, cosine ----------
__global__ __launch_bounds__(64) void k_fin(const float* __restrict__ part,
                                            const float* __restrict__ wOut,
                                            const float* __restrict__ bOut,
                                            float* __restrict__ dout)
{
    const int b = blockIdx.x, d = threadIdx.x;
    __shared__ float m1[64], m2[64];
    m1[d] = part[(b * 4 + 0) * 64 + d] + part[(b * 4 + 1) * 64 + d] +
            part[(b * 4 + 2) * 64 + d] + part[(b * 4 + 3) * 64 + d];
    m2[d] = part[((32 + b) * 4 + 0) * 64 + d] + part[((32 + b) * 4 + 1) * 64 + d] +
            part[((32 + b) * 4 + 2) * 64 + d] + part[((32 + b) * 4 + 3) * 64 + d];
    __syncthreads();
    float a1 = bOut[d], a2 = bOut[d];
    #pragma unroll 8
    for (int k = 0; k < 64; ++k) {
        a1 += m1[k] * wOut[k * 64 + d];
        a2 += m2[k] * wOut[k * 64 + d];
    }
    float s1 = a1 * a1, s2 = a2 * a2, s3 = a1 * a2;
    #pragma unroll
    for (int m = 32; m > 0; m >>= 1) {
        s1 += __shfl_xor(s1, m);
        s2 += __shfl_xor(s2, m);
        s3 += __shfl_xor(s3, m);
    }
    if (d == 0) {
        float n1 = sqrtf(fmaxf(s1, 1e-12f));
        float n2 = sqrtf(fmaxf(s2, 1e-12f));
        dout[b] = 0.5f * (s3 / (n1 * n2) + 1.0f);
    }
}

// ---------- fp32 fallback kernels ----------
__global__ __launch_bounds__(256) void k_msg_fb(
    const int* __restrict__ cfgi1, const int* __restrict__ cfgi2,
    const float* __restrict__ ebuf, float* __restrict__ tbuf)
{
    __shared__ float cfgf[128][65];
    __shared__ float els[64][64];
    const int blk = blockIdx.x;
    const int gb_i = blk >> 3;
    const int rg = blk & 7;
    const int g = gb_i >> 5;
    const int b = gb_i & 31;
    const int n0 = rg * 128;
    const int tid = threadIdx.x;
    const int tx = tid & 7, ty = tid >> 3;

    float acc[4][8];
    #pragma unroll
    for (int i = 0; i < 4; ++i)
        #pragma unroll
        for (int c = 0; c < 8; ++c) acc[i][c] = 0.f;

    const float* ebase = ebuf + (long long)gb_i * N_ * E_;
    const int row = tid >> 1, half = tid & 1;

    for (int m0 = 0; m0 < N_; m0 += 64) {
        {
            const float4* src = (const float4*)(ebase + (long long)m0 * E_);
            float4* dst = (float4*)(&els[0][0]);
            #pragma unroll
            for (int k = 0; k < 4; ++k) dst[tid + 256 * k] = src[tid + 256 * k];
        }
        {
            const int* cp = (g ? cfgi2 : cfgi1) + ((long long)b * N_ + n0 + row) * N_ + m0 + half * 32;
            #pragma unroll
            for (int q = 0; q < 8; ++q) {
                int4 v = ((const int4*)cp)[q];
                cfgf[row][half * 32 + q * 4 + 0] = (float)v.x;
                cfgf[row][half * 32 + q * 4 + 1] = (float)v.y;
                cfgf[row][half * 32 + q * 4 + 2] = (float)v.z;
                cfgf[row][half * 32 + q * 4 + 3] = (float)v.w;
            }
        }
        __syncthreads();

        #pragma unroll 4
        for (int mm = 0; mm < 64; ++mm) {
            float4 e0 = *(const float4*)&els[mm][tx * 8];
            float4 e1 = *(const float4*)&els[mm][tx * 8 + 4];
            #pragma unroll
            for (int i = 0; i < 4; ++i) {
                float c = cfgf[ty + 32 * i][mm];
                acc[i][0] += c * e0.x; acc[i][1] += c * e0.y;
                acc[i][2] += c * e0.z; acc[i][3] += c * e0.w;
                acc[i][4] += c * e1.x; acc[i][5] += c * e1.y;
                acc[i][6] += c * e1.z; acc[i][7] += c * e1.w;
            }
        }
        __syncthreads();
    }

    float* tb = tbuf + (long long)gb_i * N_ * E_;
    #pragma unroll
    for (int i = 0; i < 4; ++i) {
        int r = n0 + ty + 32 * i;
        float4 o0 = {acc[i][0], acc[i][1], acc[i][2], acc[i][3]};
        float4 o1 = {acc[i][4], acc[i][5], acc[i][6], acc[i][7]};
        *(float4*)&tb[(long long)r * E_ + tx * 8] = o0;
        *(float4*)&tb[(long long)r * E_ + tx * 8 + 4] = o1;
    }
}

__global__ __launch_bounds__(64) void k_mlp_fb(
    const float* __restrict__ tbuf, float* __restrict__ ebuf,
    const float* __restrict__ mlpW, const float* __restrict__ mlpb)
{
    __shared__ float tls[64][65];
    __shared__ float mls[64][65];
    const int tid = threadIdx.x;
    const long long r0 = (long long)blockIdx.x * 64;

    {
        const float4* src = (const float4*)(tbuf + r0 * E_);
        #pragma unroll
        for (int i = 0; i < 16; ++i) {
            int f4 = tid + 64 * i;
            float4 v = src[f4];
            int row = f4 >> 4, col = (f4 & 15) << 2;
            tls[row][col] = v.x; tls[row][col + 1] = v.y;
            tls[row][col + 2] = v.z; tls[row][col + 3] = v.w;
        }
    }
    __syncthreads();

    for (int dc = 0; dc < 8; ++dc) {
        float a[8];
        #pragma unroll
        for (int c = 0; c < 8; ++c) a[c] = mlpb[dc * 8 + c];
        #pragma unroll 8
        for (int k = 0; k < 64; ++k) {
            float tv = tls[tid][k];
            #pragma unroll
            for (int c = 0; c < 8; ++c) a[c] += tv * mlpW[k * 64 + dc * 8 + c];
        }
        #pragma unroll
        for (int c = 0; c < 8; ++c) mls[tid][dc * 8 + c] = fmaxf(a[c], 0.f);
    }
    for (int dc = 0; dc < 8; ++dc) {
        float a[8];
        #pragma unroll
        for (int c = 0; c < 8; ++c) a[c] = mlpb[64 + dc * 8 + c];
        #pragma unroll 8
        for (int k = 0; k < 64; ++k) {
            float tv = mls[tid][k];
            #pragma unroll
            for (int c = 0; c < 8; ++c) a[c] += tv * mlpW[4096 + k * 64 + dc * 8 + c];
        }
        #pragma unroll
        for (int c = 0; c < 8; ++c) tls[tid][dc * 8 + c] = fmaxf(a[c], 0.f);
    }
    __syncthreads();

    {
        float4* eb = (float4*)(ebuf + r0 * E_);
        #pragma unroll
        for (int i = 0; i < 16; ++i) {
            int f4 = tid + 64 * i;
            int row = f4 >> 4, col = (f4 & 15) << 2;
            float4 ev = eb[f4];
            float4 o;
            o.x = tanhf(ev.x + tls[row][col]);
            o.y = tanhf(ev.y + tls[row][col + 1]);
            o.z = tanhf(ev.z + tls[row][col + 2]);
            o.w = tanhf(ev.w + tls[row][col + 3]);
            eb[f4] = o;
        }
    }
}

__global__ __launch_bounds__(64) void k_out(const float* __restrict__ ebuf,
                                            const float* __restrict__ wOut,
                                            const float* __restrict__ bOut,
                                            float* __restrict__ outws)
{
    __shared__ float mid[E_];
    const int gb_i = blockIdx.x;
    const int tid = threadIdx.x;
    const float* eb = ebuf + (long long)gb_i * N_ * E_;
    float s = 0.f;
    for (int n = 0; n < N_; ++n) s += eb[(long long)n * E_ + tid];
    mid[tid] = s;
    __syncthreads();
    float a = bOut[tid];
    #pragma unroll 8
    for (int k = 0; k < E_; ++k) a += mid[k] * wOut[k * E_ + tid];
    outws[gb_i * E_ + tid] = a;
}

__global__ __launch_bounds__(64) void k_cos(const float* __restrict__ outws,
                                            float* __restrict__ dout)
{
    const int b = blockIdx.x, d = threadIdx.x;
    float a = outws[b * E_ + d];
    float c = outws[(32 + b) * E_ + d];
    float s1 = a * a, s2 = c * c, s3 = a * c;
    #pragma unroll
    for (int m = 32; m > 0; m >>= 1) {
        s1 += __shfl_xor(s1, m);
        s2 += __shfl_xor(s2, m);
        s3 += __shfl_xor(s3, m);
    }
    if (d == 0) {
        float n1 = sqrtf(fmaxf(s1, 1e-12f));
        float n2 = sqrtf(fmaxf(s2, 1e-12f));
        dout[b] = 0.5f * (s3 / (n1 * n2) + 1.0f);
    }
}

extern "C" void kernel_launch(void* const* d_in, const int* in_sizes, int n_in,
                              void* d_out, int out_size, void* d_ws, size_t ws_size,
                              hipStream_t stream) {
    const int*   CFG1 = (const int*)d_in[0];
    const float* LIT1 = (const float*)d_in[2];
    const float* SEM1 = (const float*)d_in[3];
    const int*   CFG2 = (const int*)d_in[4];
    const float* LIT2 = (const float*)d_in[6];
    const float* SEM2 = (const float*)d_in[7];
    const float* d1_Win  = (const float*)d_in[8];
    const float* d1_bin  = (const float*)d_in[9];
    const float* d1_Wout = (const float*)d_in[10];
    const float* d1_bout = (const float*)d_in[11];
    const float* d1_gk   = (const float*)d_in[12];
    const float* d1_grk  = (const float*)d_in[13];
    const float* d1_gb   = (const float*)d_in[14];
    const float* d2_Win  = (const float*)d_in[15];
    const float* d2_bin  = (const float*)d_in[16];
    const float* d2_Wout = (const float*)d_in[17];
    const float* d2_bout = (const float*)d_in[18];
    const float* d2_gk   = (const float*)d_in[19];
    const float* d2_grk  = (const float*)d_in[20];
    const float* d2_gb   = (const float*)d_in[21];
    const float* mlpW = (const float*)d_in[22];
    const float* mlpb = (const float*)d_in[23];
    const float* wOut = (const float*)d_in[24];
    const float* bOut = (const float*)d_in[25];

    char* ws = (char*)d_ws;

    if (ws_size >= F_MIN) {
        float*   xproj = (float*)(ws + 0);            // phase-1 overlay
        short*   eT0h  = (short*)(ws + F_ET0H);
        short*   eT1h  = (short*)(ws + F_ET1H);
        float*   ebuf  = (float*)(ws + F_EBUF);
        uint8_t* cfgb  = (uint8_t*)(ws + F_CFGB);
        short*   wbuf  = (short*)(ws + F_WBUF);
        float*   part  = (float*)(ws + F_ET1L);

        k_pre<<<LITBLK + 4097, 256, 0, stream>>>(LIT1, SEM1, LIT2, SEM2,
                                                 d1_Win, d1_bin, d1_Wout, d1_bout, d1_gk, d1_gb,
                                                 d2_Win, d2_bin, d2_Wout, d2_bout, d2_gk, d2_gb,
                                                 ebuf, xproj, CFG1, CFG2, cfgb, mlpW, wbuf);

        k_gru<<<64, 64, 0, stream>>>(d1_grk, d1_gb, d2_grk, d2_gb, xproj, ebuf);

        k_etr<<<512, 256, 0, stream>>>(ebuf, eT0h);

        for (int it = 0; it < 5; ++it) {
            short* sh = (it & 1) ? eT1h : eT0h;
            short* dh = (it & 1) ? eT0h : eT1h;
            if (it < 4)
                k_msgmlp<1><<<512, 256, 0, stream>>>(cfgb, sh, dh, ebuf, wbuf, mlpb);
            else
                k_msgmlp<0><<<512, 256, 0, stream>>>(cfgb, sh, dh, ebuf, wbuf, mlpb);
        }

        k_outp<<<256, 256, 0, stream>>>(ebuf, part);
        k_fin<<<32, 64, 0, stream>>>(part, wOut, bOut, (float*)d_out);
    } else if (ws_size >= O_MIN) {
        float* xproj = (float*)(ws + O_XPROJ);
        float* tbuf  = (float*)(ws + O_T);
        float* ebuf  = (float*)(ws + O_E);
        float* outws = (float*)(ws + O_OW);

        k_pre<<<LITBLK, 256, 0, stream>>>(LIT1, SEM1, LIT2, SEM2,
                                          d1_Win, d1_bin, d1_Wout, d1_bout, d1_gk, d1_gb,
                                          d2_Win, d2_bin, d2_Wout, d2_bout, d2_gk, d2_gb,
                                          ebuf, xproj, CFG1, CFG2, (uint8_t*)ws, mlpW, (short*)ws);

        k_gru<<<64, 64, 0, stream>>>(d1_grk, d1_gb, d2_grk, d2_gb, xproj, ebuf);

        for (int it = 0; it < 5; ++it) {
            k_msg_fb<<<512, 256, 0, stream>>>(CFG1, CFG2, ebuf, tbuf);
            k_mlp_fb<<<1024, 64, 0, stream>>>(tbuf, ebuf, mlpW, mlpb);
        }

        k_out<<<GBN, 64, 0, stream>>>(ebuf, wOut, bOut, outws);
        k_cos<<<32, 64, 0, stream>>>(outws, (float*)d_out);
    }
}